// Round 1
// baseline (354.033 us; speedup 1.0000x reference)
//
#include <hip/hip_runtime.h>

typedef unsigned short u16;
typedef __attribute__((ext_vector_type(8))) short bf16x8;
typedef __attribute__((ext_vector_type(4))) float f32x4;
typedef __attribute__((ext_vector_type(4))) unsigned short u16x4;

#define DM 1024

__device__ __forceinline__ float bf2f(u16 u){
  union { unsigned int i; float f; } v; v.i = ((unsigned int)u)<<16; return v.f;
}
__device__ __forceinline__ u16 f2bf(float f){
  unsigned int x = __float_as_uint(f);
  return (u16)((x + 0x7FFFu + ((x>>16)&1u)) >> 16);   // RNE, finite inputs only
}

// ---------------- K0: ternary-quantize the 4 weight matrices ----------------
// scale = clip(mean|W_row|, 1e-5); wq = clip(rint(W/scale),-1,1) stored as bf16 (exact)
__global__ __launch_bounds__(256)
void quantize_w(const float* __restrict__ W0, const float* __restrict__ W1,
                const float* __restrict__ W2, const float* __restrict__ W3,
                u16* __restrict__ wq, float* __restrict__ wsc)
{
  const int gr   = blockIdx.x*4 + (threadIdx.x>>6);  // global row 0..4095
  const int lane = threadIdx.x & 63;
  const int mat  = gr >> 10, row = gr & 1023;
  const float* W = (mat==0)?W0:(mat==1)?W1:(mat==2)?W2:W3;
  const float* wr = W + (size_t)row*DM;
  float4 v[4]; float s = 0.f;
  #pragma unroll
  for (int c=0;c<4;c++){
    v[c] = *(const float4*)&wr[c*256 + lane*4];
    s += fabsf(v[c].x)+fabsf(v[c].y)+fabsf(v[c].z)+fabsf(v[c].w);
  }
  #pragma unroll
  for (int off=32; off; off>>=1) s += __shfl_down(s, off);
  s = __shfl(s, 0);
  const float scale = fmaxf(s*(1.f/1024.f), 1e-5f);
  if (lane==0) wsc[gr] = scale;
  u16* wo = wq + (size_t)gr*DM;
  #pragma unroll
  for (int c=0;c<4;c++){
    u16x4 q;
    q[0] = f2bf(fminf(fmaxf(rintf(v[c].x/scale),-1.f),1.f));
    q[1] = f2bf(fminf(fmaxf(rintf(v[c].y/scale),-1.f),1.f));
    q[2] = f2bf(fminf(fmaxf(rintf(v[c].z/scale),-1.f),1.f));
    q[3] = f2bf(fminf(fmaxf(rintf(v[c].w/scale),-1.f),1.f));
    *(u16x4*)&wo[c*256 + lane*4] = q;
  }
}

// ---------------- K1: x f32 -> bf16 ----------------
__global__ void cvt_x(const float* __restrict__ x, u16* __restrict__ xb){
  const int i = (blockIdx.x*256 + threadIdx.x)*4;
  float4 v = *(const float4*)&x[i];
  u16x4 o; o[0]=f2bf(v.x); o[1]=f2bf(v.y); o[2]=f2bf(v.z); o[3]=f2bf(v.w);
  *(u16x4*)&xb[i] = o;
}

// ---------------- K2/K6: quantized bf16 MFMA GEMM, 128x128 tile, BK=64 ----------------
// out[i,n] = bscale[n] * sum_k A[i,k]*Bq[n,k]
// MODE 0: N=3072, seg0 -> sigmoid -> r (bf16), seg1 -> k, seg2 -> v
// MODE 1: N=1024, f32 out
template<int MODE>
__global__ __launch_bounds__(256)
void gemm_q(const u16* __restrict__ A, const u16* __restrict__ Bq,
            const float* __restrict__ bscale,
            u16* __restrict__ o_r, u16* __restrict__ o_k, u16* __restrict__ o_v,
            float* __restrict__ o_f)
{
  __shared__ u16 lA[128*64];   // [row][k], 128B rows
  __shared__ u16 lB[128*64];
  const int tid = threadIdx.x;
  const int m0 = blockIdx.x*128, n0 = blockIdx.y*128;
  const int wave = tid>>6, lane = tid&63;
  const int wm = (wave>>1)*64, wn = (wave&1)*64;   // 2x2 waves, 64x64 each
  const int lr = lane&15, lg = lane>>4;
  const int K = 1024;

  f32x4 acc[4][4];
  #pragma unroll
  for (int i=0;i<4;i++)
    #pragma unroll
    for (int j=0;j<4;j++) acc[i][j] = (f32x4){0.f,0.f,0.f,0.f};

  for (int k0=0; k0<K; k0+=64){
    // stage: 16KB each, 4 calls x (256 thr x 16B). LDS dest = wave-uniform base + lane*16.
    #pragma unroll
    for (int c=0;c<4;c++){
      const int idx  = c*256 + tid;
      const int row  = idx >> 3;          // 8 threads per 128B row
      const int colb = (idx & 7) << 4;
      const char* ga = (const char*)(A  + (size_t)(m0+row)*K) + k0*2 + colb;
      const char* gb = (const char*)(Bq + (size_t)(n0+row)*K) + k0*2 + colb;
      char* la = (char*)lA + ((idx>>6)<<10);
      char* lb = (char*)lB + ((idx>>6)<<10);
      __builtin_amdgcn_global_load_lds((const __attribute__((address_space(1))) void*)ga,
                                       (__attribute__((address_space(3))) void*)la, 16, 0, 0);
      __builtin_amdgcn_global_load_lds((const __attribute__((address_space(1))) void*)gb,
                                       (__attribute__((address_space(3))) void*)lb, 16, 0, 0);
    }
    __syncthreads();
    #pragma unroll
    for (int ks=0; ks<2; ++ks){
      bf16x8 af[4], bfv[4];
      #pragma unroll
      for (int mi=0; mi<4; ++mi)
        af[mi] = *(const bf16x8*)&lA[(wm + mi*16 + lr)*64 + ks*32 + lg*8];
      #pragma unroll
      for (int ni=0; ni<4; ++ni)
        bfv[ni] = *(const bf16x8*)&lB[(wn + ni*16 + lr)*64 + ks*32 + lg*8];
      #pragma unroll
      for (int mi=0; mi<4; ++mi)
        #pragma unroll
        for (int ni=0; ni<4; ++ni)
          acc[mi][ni] = __builtin_amdgcn_mfma_f32_16x16x32_bf16(af[mi], bfv[ni], acc[mi][ni], 0, 0, 0);
    }
    __syncthreads();
  }

  #pragma unroll
  for (int mi=0; mi<4; ++mi){
    #pragma unroll
    for (int ni=0; ni<4; ++ni){
      const int col = n0 + wn + ni*16 + lr;
      const float sc = bscale[col];
      const f32x4 a = acc[mi][ni];
      #pragma unroll
      for (int r2=0; r2<4; ++r2){
        const int rowi = m0 + wm + mi*16 + lg*4 + r2;   // C/D: col=lane&15, row=(lane>>4)*4+reg
        const float val = a[r2]*sc;
        if (MODE==0){
          const int seg = col >> 10, d = col & 1023;    // seg uniform per block (1024%128==0)
          const size_t o = (size_t)rowi*DM + d;
          if (seg==0)      o_r[o] = f2bf(1.f/(1.f+expf(-val)));
          else if (seg==1) o_k[o] = f2bf(val);
          else             o_v[o] = f2bf(val);
        } else {
          o_f[(size_t)rowi*DM + col] = val;
        }
      }
    }
  }
}

// ---------------- K3: scaled = k*v / max(exp(t*ld),1e-10); per-chunk sums ----------------
// grid: 256 blocks = (chunk c in [0,64)) x (batch b in [0,4)); 256 thr x 4 d = full D
__global__ __launch_bounds__(256)
void kv_phase1(const u16* __restrict__ kb, const u16* __restrict__ vb,
               const float* __restrict__ decay,
               float* __restrict__ scaled, float* __restrict__ part)
{
  const int c = blockIdx.x & 63, b = blockIdx.x >> 6;
  const int d0 = threadIdx.x*4;
  float ld[4]; f32x4 sum = {0.f,0.f,0.f,0.f};
  #pragma unroll
  for (int j=0;j<4;j++){
    const float dec = 1.f/(1.f+expf(-decay[d0+j]));
    ld[j] = logf(fmaxf(dec, 1e-7f));
  }
  for (int t=c*64; t<c*64+64; ++t){
    const size_t base = ((size_t)(b*4096 + t))*DM + d0;
    const u16x4 k4 = *(const u16x4*)&kb[base];
    const u16x4 v4 = *(const u16x4*)&vb[base];
    const float tf = (float)t;
    f32x4 o;
    #pragma unroll
    for (int j=0;j<4;j++){
      const float sct = expf(tf*ld[j]);                      // underflows to 0 like ref
      const float val = bf2f(k4[j])*bf2f(v4[j]) / fmaxf(sct, 1e-10f);
      o[j] = val; sum[j] += val;
    }
    *(f32x4*)&scaled[base] = o;
  }
  *(f32x4*)&part[((size_t)(b*64+c))*DM + d0] = sum;
}

// ---------------- K4: exclusive prefix over the 64 chunk sums ----------------
__global__ void chunk_prefix(float* __restrict__ part){
  const int g = blockIdx.x*256 + threadIdx.x;  // 0..1023
  const int b = g >> 8, d0 = (g & 255)*4;
  f32x4 run = {0.f,0.f,0.f,0.f};
  for (int c=0;c<64;c++){
    f32x4* p = (f32x4*)&part[((size_t)(b*64+c))*DM + d0];
    f32x4 v = *p;
    *p = run;
    run += v;
  }
}

// ---------------- K5: in-chunk scan + state + y=r*state + rmsnorm -> ynorm bf16 ----------------
// block covers full D row (256 thr x 4 d); 2 barriers per t for the row reduction
__global__ __launch_bounds__(256)
void scan_norm(const float* __restrict__ scaled, const u16* __restrict__ rbuf,
               const float* __restrict__ part, const float* __restrict__ decay,
               const float* __restrict__ lnw, u16* __restrict__ yn)
{
  const int c = blockIdx.x & 63, b = blockIdx.x >> 6;
  const int tid = threadIdx.x, lane = tid&63, wave = tid>>6;
  const int d0 = tid*4;
  __shared__ float red[4];
  __shared__ float tot;
  f32x4 run = *(const f32x4*)&part[((size_t)(b*64+c))*DM + d0];
  float ld[4], lw[4];
  #pragma unroll
  for (int j=0;j<4;j++){
    const float dec = 1.f/(1.f+expf(-decay[d0+j]));
    ld[j] = logf(fmaxf(dec, 1e-7f));
    lw[j] = lnw[d0+j];
  }
  for (int t=c*64; t<c*64+64; ++t){
    const size_t base = ((size_t)(b*4096+t))*DM + d0;
    const f32x4 s4 = *(const f32x4*)&scaled[base];
    const u16x4 r4 = *(const u16x4*)&rbuf[base];
    const float tf = (float)t;
    float y[4]; float ss = 0.f;
    #pragma unroll
    for (int j=0;j<4;j++){
      run[j] += s4[j];
      const float st = run[j]*expf(tf*ld[j]);   // unclipped scale (0 for large t) like ref
      y[j] = bf2f(r4[j])*st;
      ss += y[j]*y[j];
    }
    #pragma unroll
    for (int off=32; off; off>>=1) ss += __shfl_down(ss, off);
    if (lane==0) red[wave] = ss;
    __syncthreads();
    if (tid==0) tot = (red[0]+red[1])+(red[2]+red[3]);
    __syncthreads();
    const float rs = 1.f/sqrtf(tot*(1.f/1024.f) + 1e-6f);
    u16x4 o;
    #pragma unroll
    for (int j=0;j<4;j++) o[j] = f2bf(y[j]*rs*lw[j]);
    *(u16x4*)&yn[base] = o;
  }
}

extern "C" void kernel_launch(void* const* d_in, const int* in_sizes, int n_in,
                              void* d_out, int out_size, void* d_ws, size_t ws_size,
                              hipStream_t stream)
{
  (void)in_sizes; (void)n_in; (void)out_size; (void)ws_size;
  const float* x    = (const float*)d_in[0];
  const float* Wr   = (const float*)d_in[1];
  const float* Wk   = (const float*)d_in[2];
  const float* Wv   = (const float*)d_in[3];
  const float* Wo   = (const float*)d_in[4];
  const float* dec  = (const float*)d_in[5];
  const float* lnw  = (const float*)d_in[6];

  // workspace layout (lifetimes allow aliasing):
  //   wq     [0,            8,388,608)   bf16 ternary weights, rows: R|K|V|O
  //   wsc    [8,388,608,    8,404,992)   per-row scales (4096 f32)
  //   rbuf   [8,404,992,   41,959,424)   r bf16                (K2 -> K5)
  //   kbuf   [41,959,424,  75,513,856)   k bf16 (K2->K3), then REUSED as ynorm (K5->K6)
  //   vbuf   [75,513,856, 109,068,288)   v bf16                (K2 -> K3)
  //   part   [109,068,288,110,116,864)   chunk partials        (K3 -> K5)
  //   scaled [110,116,864,177,225,728)   f32; first half aliases xb bf16 (K1 -> K2)
  char* ws = (char*)d_ws;
  u16*   wq     = (u16*)(ws + 0);
  float* wsc    = (float*)(ws + 8388608);
  u16*   rbuf   = (u16*)(ws + 8404992);
  u16*   kbuf   = (u16*)(ws + 41959424);
  u16*   vbuf   = (u16*)(ws + 75513856);
  float* part   = (float*)(ws + 109068288);
  float* scaled = (float*)(ws + 110116864);
  u16*   xb     = (u16*)(ws + 110116864);
  u16*   yn     = kbuf;

  quantize_w<<<1024, 256, 0, stream>>>(Wr, Wk, Wv, Wo, wq, wsc);
  cvt_x<<<16384, 256, 0, stream>>>(x, xb);
  gemm_q<0><<<dim3(128,24), 256, 0, stream>>>(xb, wq, wsc, rbuf, kbuf, vbuf, nullptr);
  kv_phase1<<<256, 256, 0, stream>>>(kbuf, vbuf, dec, scaled, part);
  chunk_prefix<<<4, 256, 0, stream>>>(part);
  scan_norm<<<256, 256, 0, stream>>>(scaled, rbuf, part, dec, lnw, yn);
  gemm_q<1><<<dim3(128,8), 256, 0, stream>>>(yn, wq + 3*1024*1024, wsc + 3072,
                                             nullptr, nullptr, nullptr, (float*)d_out);
}

// Round 2
// 298.593 us; speedup vs baseline: 1.1857x; 1.1857x over previous
//
#include <hip/hip_runtime.h>

typedef unsigned short u16;
typedef __attribute__((ext_vector_type(8))) short bf16x8;
typedef __attribute__((ext_vector_type(4))) float f32x4;
typedef __attribute__((ext_vector_type(4))) unsigned short u16x4;

#define DM 1024

__device__ __forceinline__ float bf2f(u16 u){
  union { unsigned int i; float f; } v; v.i = ((unsigned int)u)<<16; return v.f;
}
__device__ __forceinline__ u16 f2bf(float f){
  unsigned int x = __float_as_uint(f);
  return (u16)((x + 0x7FFFu + ((x>>16)&1u)) >> 16);   // RNE, finite inputs only
}

// ---------------- K0: ternary-quantize the 4 weight matrices ----------------
__global__ __launch_bounds__(256)
void quantize_w(const float* __restrict__ W0, const float* __restrict__ W1,
                const float* __restrict__ W2, const float* __restrict__ W3,
                u16* __restrict__ wq, float* __restrict__ wsc)
{
  const int gr   = blockIdx.x*4 + (threadIdx.x>>6);  // global row 0..4095
  const int lane = threadIdx.x & 63;
  const int mat  = gr >> 10, row = gr & 1023;
  const float* W = (mat==0)?W0:(mat==1)?W1:(mat==2)?W2:W3;
  const float* wr = W + (size_t)row*DM;
  float4 v[4]; float s = 0.f;
  #pragma unroll
  for (int c=0;c<4;c++){
    v[c] = *(const float4*)&wr[c*256 + lane*4];
    s += fabsf(v[c].x)+fabsf(v[c].y)+fabsf(v[c].z)+fabsf(v[c].w);
  }
  #pragma unroll
  for (int off=32; off; off>>=1) s += __shfl_down(s, off);
  s = __shfl(s, 0);
  const float scale = fmaxf(s*(1.f/1024.f), 1e-5f);
  if (lane==0) wsc[gr] = scale;
  u16* wo = wq + (size_t)gr*DM;
  #pragma unroll
  for (int c=0;c<4;c++){
    u16x4 q;
    q[0] = f2bf(fminf(fmaxf(rintf(v[c].x/scale),-1.f),1.f));
    q[1] = f2bf(fminf(fmaxf(rintf(v[c].y/scale),-1.f),1.f));
    q[2] = f2bf(fminf(fmaxf(rintf(v[c].z/scale),-1.f),1.f));
    q[3] = f2bf(fminf(fmaxf(rintf(v[c].w/scale),-1.f),1.f));
    *(u16x4*)&wo[c*256 + lane*4] = q;
  }
}

// ---------------- K1: x f32 -> bf16 ----------------
__global__ void cvt_x(const float* __restrict__ x, u16* __restrict__ xb){
  const int i = (blockIdx.x*256 + threadIdx.x)*4;
  float4 v = *(const float4*)&x[i];
  u16x4 o; o[0]=f2bf(v.x); o[1]=f2bf(v.y); o[2]=f2bf(v.z); o[3]=f2bf(v.w);
  *(u16x4*)&xb[i] = o;
}

// ---------------- K2/K6: 256x256 deep-pipelined MFMA GEMM, BK=64 ----------------
// out[i,n] = bscale[n] * sum_k A[i,k]*Bq[n,k]
// 8 waves (2M x 4N), per-wave C = 128x64. 2 LDS buffers, prefetch distance 2 tiles,
// counted vmcnt(6) at tile boundary, stage-issues into freed sub-regions:
//   p0: A1,A3 of t+1 (other buf) | p1: B0,B1 of t+2 | p2: A0,A2 of t+2 | p3: B2,B3 of t+2
// B-frags register-resident after p0 (B-buf free); A frees 32-row bands per phase.
// XOR swizzle col^=(row&7)<<4 on stage-source AND ds_read (involution, rule 21).

__device__ __forceinline__ void stage_issue(const u16* __restrict__ gbase, int grow0,
                                            int tt, int q, u16* lbuf, int wave, int lane)
{
  const int r8    = lane>>3;            // 0..7 == (lrow & 7)
  const int lrow0 = q*64 + wave*8;      // wave-uniform row base (multiple of 8)
  const int colb  = (lane&7)<<4;
  const int scol  = colb ^ (r8<<4);     // pre-swizzled global source col
  const char* src = (const char*)(gbase + (size_t)(grow0 + lrow0 + r8)*DM) + tt*128 + scol;
  char* dst = (char*)lbuf + lrow0*128;  // linear LDS dest: HW adds lane*16
  __builtin_amdgcn_global_load_lds((const __attribute__((address_space(1))) void*)src,
                                   (__attribute__((address_space(3))) void*)dst, 16, 0, 0);
}

__device__ __forceinline__ bf16x8 ldsF(const u16* lbuf, int row, int ks, int lg){
  const int cb = ((ks<<6) + (lg<<4)) ^ ((row&7)<<4);
  return *(const bf16x8*)((const char*)lbuf + row*128 + cb);
}

#define PHASE(MI0)                                                                              \
  {                                                                                             \
    bf16x8 af0k0 = ldsF(la, wm*128 + (MI0)*16   + lr, 0, lg);                                   \
    bf16x8 af0k1 = ldsF(la, wm*128 + (MI0)*16   + lr, 1, lg);                                   \
    bf16x8 af1k0 = ldsF(la, wm*128 + (MI0+1)*16 + lr, 0, lg);                                   \
    bf16x8 af1k1 = ldsF(la, wm*128 + (MI0+1)*16 + lr, 1, lg);                                   \
    __builtin_amdgcn_s_setprio(1);                                                              \
    _Pragma("unroll")                                                                           \
    for (int ni=0; ni<4; ++ni){                                                                 \
      acc[MI0][ni]   = __builtin_amdgcn_mfma_f32_16x16x32_bf16(af0k0, bf_[0][ni], acc[MI0][ni],   0,0,0); \
      acc[MI0][ni]   = __builtin_amdgcn_mfma_f32_16x16x32_bf16(af0k1, bf_[1][ni], acc[MI0][ni],   0,0,0); \
      acc[MI0+1][ni] = __builtin_amdgcn_mfma_f32_16x16x32_bf16(af1k0, bf_[0][ni], acc[MI0+1][ni], 0,0,0); \
      acc[MI0+1][ni] = __builtin_amdgcn_mfma_f32_16x16x32_bf16(af1k1, bf_[1][ni], acc[MI0+1][ni], 0,0,0); \
    }                                                                                           \
    __builtin_amdgcn_s_setprio(0);                                                              \
  }

#define FENCE() __builtin_amdgcn_sched_barrier(0)
#define BAR()   do { FENCE(); __builtin_amdgcn_s_barrier(); asm volatile("" ::: "memory"); FENCE(); } while(0)

template<int MODE>
__global__ __launch_bounds__(512, 2)
void gemm_q8(const u16* __restrict__ A, const u16* __restrict__ Bq,
             const float* __restrict__ bscale,
             u16* __restrict__ o_r, u16* __restrict__ o_k, u16* __restrict__ o_v,
             float* __restrict__ o_f)
{
  __shared__ u16 sA[2][256*64];
  __shared__ u16 sB[2][256*64];
  const int tid = threadIdx.x, wave = tid>>6, lane = tid&63;
  const int lr = lane&15, lg = lane>>4;
  const int wm = wave>>2, wn = wave&3;
  const int bm0 = blockIdx.x*256, bn0 = blockIdx.y*256;
  const int nt = 16;                       // K = 1024 / BK=64

  f32x4 acc[8][4];
  #pragma unroll
  for (int i=0;i<8;i++)
    #pragma unroll
    for (int j=0;j<4;j++) acc[i][j] = (f32x4){0.f,0.f,0.f,0.f};

  // prologue: tile 0 fully; tile 1 all but A1,A3 (those go at t=0 p0)
  #pragma unroll
  for (int q=0;q<4;q++){
    stage_issue(A,  bm0, 0, q, sA[0], wave, lane);
    stage_issue(Bq, bn0, 0, q, sB[0], wave, lane);
  }
  FENCE();
  stage_issue(Bq, bn0, 1, 0, sB[1], wave, lane);
  stage_issue(Bq, bn0, 1, 1, sB[1], wave, lane);
  stage_issue(A,  bm0, 1, 0, sA[1], wave, lane);
  stage_issue(A,  bm0, 1, 2, sA[1], wave, lane);
  stage_issue(Bq, bn0, 1, 2, sB[1], wave, lane);
  stage_issue(Bq, bn0, 1, 3, sB[1], wave, lane);

  for (int t=0; t<nt; ++t){
    const int c = t&1;
    const u16* la = sA[c];
    const u16* lb = sB[c];
    // ---- tile boundary: counted wait (never 0), then converge ----
    FENCE();
    asm volatile("s_waitcnt vmcnt(6)" ::: "memory");
    __builtin_amdgcn_s_barrier();
    asm volatile("" ::: "memory");
    FENCE();
    // ---- phase 0: stage A1,A3 of t+1; read all B-frags + A mi0,1; 16 MFMA ----
    if (t+1 < nt){
      stage_issue(A, bm0, t+1, 1, sA[c^1], wave, lane);
      stage_issue(A, bm0, t+1, 3, sA[c^1], wave, lane);
    }
    bf16x8 bf_[2][4];
    #pragma unroll
    for (int ks=0;ks<2;ks++)
      #pragma unroll
      for (int ni=0;ni<4;ni++)
        bf_[ks][ni] = ldsF(lb, wn*64 + ni*16 + lr, ks, lg);
    PHASE(0)
    BAR();
    // ---- phase 1: stage B0,B1 of t+2; A mi2,3 ----
    if (t+2 < nt){
      stage_issue(Bq, bn0, t+2, 0, sB[c], wave, lane);
      stage_issue(Bq, bn0, t+2, 1, sB[c], wave, lane);
    }
    PHASE(2)
    BAR();
    // ---- phase 2: stage A0,A2 of t+2; A mi4,5 ---- (no barrier to phase 3: regions disjoint)
    if (t+2 < nt){
      stage_issue(A, bm0, t+2, 0, sA[c], wave, lane);
      stage_issue(A, bm0, t+2, 2, sA[c], wave, lane);
    }
    PHASE(4)
    // ---- phase 3: stage B2,B3 of t+2; A mi6,7 ----
    if (t+2 < nt){
      stage_issue(Bq, bn0, t+2, 2, sB[c], wave, lane);
      stage_issue(Bq, bn0, t+2, 3, sB[c], wave, lane);
    }
    PHASE(6)
  }

  // ---- epilogue ----
  #pragma unroll
  for (int mi=0; mi<8; ++mi){
    #pragma unroll
    for (int ni=0; ni<4; ++ni){
      const int col = bn0 + wn*64 + ni*16 + lr;
      const float sc = bscale[col];
      const int rowb = bm0 + wm*128 + mi*16 + lg*4;
      const f32x4 a = acc[mi][ni];
      if (MODE==0){
        const int seg = col>>10, d = col&1023;
        #pragma unroll
        for (int r2=0;r2<4;r2++){
          const size_t o = (size_t)(rowb+r2)*DM + d;
          const float val = a[r2]*sc;
          if (seg==0)      o_r[o] = f2bf(1.f/(1.f+expf(-val)));
          else if (seg==1) o_k[o] = f2bf(val);
          else             o_v[o] = f2bf(val);
        }
      } else {
        #pragma unroll
        for (int r2=0;r2<4;r2++)
          o_f[(size_t)(rowb+r2)*DM + col] = a[r2]*sc;
      }
    }
  }
}

// ---------------- K3: scaled = k*v / max(exp(t*ld),1e-10); per-chunk sums ----------------
__global__ __launch_bounds__(256)
void kv_phase1(const u16* __restrict__ kb, const u16* __restrict__ vb,
               const float* __restrict__ decay,
               float* __restrict__ scaled, float* __restrict__ part)
{
  const int c = blockIdx.x & 63, b = blockIdx.x >> 6;
  const int d0 = threadIdx.x*4;
  float ld[4]; f32x4 sum = {0.f,0.f,0.f,0.f};
  #pragma unroll
  for (int j=0;j<4;j++){
    const float dec = 1.f/(1.f+expf(-decay[d0+j]));
    ld[j] = logf(fmaxf(dec, 1e-7f));
  }
  for (int t=c*64; t<c*64+64; ++t){
    const size_t base = ((size_t)(b*4096 + t))*DM + d0;
    const u16x4 k4 = *(const u16x4*)&kb[base];
    const u16x4 v4 = *(const u16x4*)&vb[base];
    const float tf = (float)t;
    f32x4 o;
    #pragma unroll
    for (int j=0;j<4;j++){
      const float sct = expf(tf*ld[j]);                      // underflows to 0 like ref
      const float val = bf2f(k4[j])*bf2f(v4[j]) / fmaxf(sct, 1e-10f);
      o[j] = val; sum[j] += val;
    }
    *(f32x4*)&scaled[base] = o;
  }
  *(f32x4*)&part[((size_t)(b*64+c))*DM + d0] = sum;
}

// ---------------- K4: exclusive prefix over the 64 chunk sums ----------------
__global__ void chunk_prefix(float* __restrict__ part){
  const int g = blockIdx.x*256 + threadIdx.x;  // 0..1023
  const int b = g >> 8, d0 = (g & 255)*4;
  f32x4 run = {0.f,0.f,0.f,0.f};
  for (int c=0;c<64;c++){
    f32x4* p = (f32x4*)&part[((size_t)(b*64+c))*DM + d0];
    f32x4 v = *p;
    *p = run;
    run += v;
  }
}

// ---------------- K5: in-chunk scan + state + y=r*state + rmsnorm -> ynorm bf16 ----------------
__global__ __launch_bounds__(256)
void scan_norm(const float* __restrict__ scaled, const u16* __restrict__ rbuf,
               const float* __restrict__ part, const float* __restrict__ decay,
               const float* __restrict__ lnw, u16* __restrict__ yn)
{
  const int c = blockIdx.x & 63, b = blockIdx.x >> 6;
  const int tid = threadIdx.x, lane = tid&63, wave = tid>>6;
  const int d0 = tid*4;
  __shared__ float red[4];
  __shared__ float tot;
  f32x4 run = *(const f32x4*)&part[((size_t)(b*64+c))*DM + d0];
  float ld[4], lw[4];
  #pragma unroll
  for (int j=0;j<4;j++){
    const float dec = 1.f/(1.f+expf(-decay[d0+j]));
    ld[j] = logf(fmaxf(dec, 1e-7f));
    lw[j] = lnw[d0+j];
  }
  for (int t=c*64; t<c*64+64; ++t){
    const size_t base = ((size_t)(b*4096+t))*DM + d0;
    const f32x4 s4 = *(const f32x4*)&scaled[base];
    const u16x4 r4 = *(const u16x4*)&rbuf[base];
    const float tf = (float)t;
    float y[4]; float ss = 0.f;
    #pragma unroll
    for (int j=0;j<4;j++){
      run[j] += s4[j];
      const float st = run[j]*expf(tf*ld[j]);   // unclipped scale (0 for large t) like ref
      y[j] = bf2f(r4[j])*st;
      ss += y[j]*y[j];
    }
    #pragma unroll
    for (int off=32; off; off>>=1) ss += __shfl_down(ss, off);
    if (lane==0) red[wave] = ss;
    __syncthreads();
    if (tid==0) tot = (red[0]+red[1])+(red[2]+red[3]);
    __syncthreads();
    const float rs = 1.f/sqrtf(tot*(1.f/1024.f) + 1e-6f);
    u16x4 o;
    #pragma unroll
    for (int j=0;j<4;j++) o[j] = f2bf(y[j]*rs*lw[j]);
    *(u16x4*)&yn[base] = o;
  }
}

extern "C" void kernel_launch(void* const* d_in, const int* in_sizes, int n_in,
                              void* d_out, int out_size, void* d_ws, size_t ws_size,
                              hipStream_t stream)
{
  (void)in_sizes; (void)n_in; (void)out_size; (void)ws_size;
  const float* x    = (const float*)d_in[0];
  const float* Wr   = (const float*)d_in[1];
  const float* Wk   = (const float*)d_in[2];
  const float* Wv   = (const float*)d_in[3];
  const float* Wo   = (const float*)d_in[4];
  const float* dec  = (const float*)d_in[5];
  const float* lnw  = (const float*)d_in[6];

  char* ws = (char*)d_ws;
  u16*   wq     = (u16*)(ws + 0);
  float* wsc    = (float*)(ws + 8388608);
  u16*   rbuf   = (u16*)(ws + 8404992);
  u16*   kbuf   = (u16*)(ws + 41959424);
  u16*   vbuf   = (u16*)(ws + 75513856);
  float* part   = (float*)(ws + 109068288);
  float* scaled = (float*)(ws + 110116864);
  u16*   xb     = (u16*)(ws + 110116864);
  u16*   yn     = kbuf;

  quantize_w<<<1024, 256, 0, stream>>>(Wr, Wk, Wv, Wo, wq, wsc);
  cvt_x<<<16384, 256, 0, stream>>>(x, xb);
  gemm_q8<0><<<dim3(64,12), 512, 0, stream>>>(xb, wq, wsc, rbuf, kbuf, vbuf, nullptr);
  kv_phase1<<<256, 256, 0, stream>>>(kbuf, vbuf, dec, scaled, part);
  chunk_prefix<<<4, 256, 0, stream>>>(part);
  scan_norm<<<256, 256, 0, stream>>>(scaled, rbuf, part, dec, lnw, yn);
  gemm_q8<1><<<dim3(64,4), 512, 0, stream>>>(yn, wq + 3*1024*1024, wsc + 3072,
                                             nullptr, nullptr, nullptr, (float*)d_out);
}